// Round 1
// baseline (3751.901 us; speedup 1.0000x reference)
//
#include <hip/hip_runtime.h>

#define GG 64
#define HH 16
#define CC 4
#define KK 64   // H*C

__device__ __forceinline__ unsigned fmap(float f){
  unsigned u = __float_as_uint(f);
  return (u & 0x80000000u) ? ~u : (u | 0x80000000u);
}
__device__ __forceinline__ float funmap(unsigned u){
  return (u & 0x80000000u) ? __uint_as_float(u ^ 0x80000000u) : __uint_as_float(~u);
}

// K1: in-degree + edge_attr sum per dst
__global__ void k_deg(const int* __restrict__ ei, const float* __restrict__ ea,
                      float* deg, float* asum, int E){
  int e = blockIdx.x*blockDim.x + threadIdx.x;
  if (e >= E) return;
  int d = ei[E + e];
  atomicAdd(&deg[d], 1.0f);
  atomicAdd(&asum[d], ea[e]);
}

// K2: loop_attr = asum / max(deg,1)  (in place on asum)
__global__ void k_loopattr(float* asum, const float* __restrict__ deg, int N){
  int i = blockIdx.x*blockDim.x + threadIdx.x;
  if (i < N) asum[i] = asum[i] / fmaxf(deg[i], 1.0f);
}

// K3: per-edge scores -> atomicMax into mapped-uint smax
__global__ void k_scoremax(const float* __restrict__ x, const int* __restrict__ ei,
                           const float* __restrict__ ea_, const float* __restrict__ loop_attr,
                           const float* __restrict__ Wl, const float* __restrict__ bl,
                           const float* __restrict__ Wr, const float* __restrict__ br,
                           const float* __restrict__ We, const float* __restrict__ att,
                           unsigned* smax_u, int N, int E){
  __shared__ float sW[6*KK];
  for (int i = threadIdx.x; i < 6*KK; i += blockDim.x){
    int a = i >> 6, b = i & 63;
    const float* p = (a==0)?Wl:(a==1)?bl:(a==2)?Wr:(a==3)?br:(a==4)?We:att;
    sW[i] = p[b];
  }
  __syncthreads();
  int e = blockIdx.x*blockDim.x + threadIdx.x;
  int T = E + N;
  if (e >= T) return;
  int s, d; float ea;
  if (e < E){ s = ei[e]; d = ei[E+e]; ea = ea_[e]; }
  else { s = d = e - E; ea = loop_attr[s]; }
  float xs = x[s], xd = x[d];
  #pragma unroll
  for (int h = 0; h < HH; ++h){
    float sc = 0.f;
    #pragma unroll
    for (int c = 0; c < CC; ++c){
      int k = h*CC + c;
      float t = fmaf(xs, sW[k], sW[64+k]) + fmaf(xd, sW[128+k], sW[192+k]) + ea*sW[256+k];
      t = (t > 0.f) ? t : 0.2f*t;
      sc = fmaf(t, sW[320+k], sc);
    }
    atomicMax(&smax_u[d*HH + h], fmap(sc));
  }
}

// K4: unmap smax in place (uint -> float)
__global__ void k_unmap(unsigned* u, int n){
  int i = blockIdx.x*blockDim.x + threadIdx.x;
  if (i < n) ((float*)u)[i] = funmap(u[i]);
}

// K5: per-edge a = exp(score - smax[dst]); accumulate denom and S1 = sum a*x_src
__global__ void k_scoreacc(const float* __restrict__ x, const int* __restrict__ ei,
                           const float* __restrict__ ea_, const float* __restrict__ loop_attr,
                           const float* __restrict__ Wl, const float* __restrict__ bl,
                           const float* __restrict__ Wr, const float* __restrict__ br,
                           const float* __restrict__ We, const float* __restrict__ att,
                           const float* __restrict__ smax, float* denom, float* S1,
                           int N, int E){
  __shared__ float sW[6*KK];
  for (int i = threadIdx.x; i < 6*KK; i += blockDim.x){
    int a = i >> 6, b = i & 63;
    const float* p = (a==0)?Wl:(a==1)?bl:(a==2)?Wr:(a==3)?br:(a==4)?We:att;
    sW[i] = p[b];
  }
  __syncthreads();
  int e = blockIdx.x*blockDim.x + threadIdx.x;
  int T = E + N;
  if (e >= T) return;
  int s, d; float ea;
  if (e < E){ s = ei[e]; d = ei[E+e]; ea = ea_[e]; }
  else { s = d = e - E; ea = loop_attr[s]; }
  float xs = x[s], xd = x[d];
  #pragma unroll
  for (int h = 0; h < HH; ++h){
    float sc = 0.f;
    #pragma unroll
    for (int c = 0; c < CC; ++c){
      int k = h*CC + c;
      float t = fmaf(xs, sW[k], sW[64+k]) + fmaf(xd, sW[128+k], sW[192+k]) + ea*sW[256+k];
      t = (t > 0.f) ? t : 0.2f*t;
      sc = fmaf(t, sW[320+k], sc);
    }
    float a = expf(sc - smax[d*HH + h]);
    atomicAdd(&denom[d*HH + h], a);
    atomicAdd(&S1[d*HH + h], a*xs);
  }
}

// K6: GAT output h_gat = relu(Wl*r + bl + gat_bias), accumulate group stats
__global__ void k_gatout(const float* __restrict__ S1, const float* __restrict__ denom,
                         const int* __restrict__ batch,
                         const float* __restrict__ Wl, const float* __restrict__ bl,
                         const float* __restrict__ gat_bias,
                         float* h_gat, float* gsum, float* gsum2, float* gcnt, int N){
  int gid = blockIdx.x*blockDim.x + threadIdx.x;
  if (gid >= N*KK) return;
  int n = gid >> 6, k = gid & 63;
  int h = k >> 2;
  float r = S1[n*HH+h] / denom[n*HH+h];
  float v = fmaxf(Wl[k]*r + bl[k] + gat_bias[k], 0.f);
  h_gat[gid] = v;
  int b = batch[n];
  atomicAdd(&gsum[b*KK+k], v);
  atomicAdd(&gsum2[b*KK+k], v*v);
  if (k == 0) atomicAdd(&gcnt[b], 1.0f);
}

// K7: groupnorm coefficients
__global__ void k_gncoef(const float* __restrict__ gsum, const float* __restrict__ gsum2,
                         const float* __restrict__ gcnt,
                         const float* __restrict__ gn_w, const float* __restrict__ gn_b,
                         const float* __restrict__ gn_ms,
                         float* scale, float* shift){
  int i = blockIdx.x*blockDim.x + threadIdx.x;
  if (i >= GG*KK) return;
  int g = i >> 6, k = i & 63;
  float c = fmaxf(gcnt[g], 1.0f);
  float mean = gsum[i]/c;
  float eh2  = gsum2[i]/c;
  float ms = gn_ms[k];
  float var = eh2 - 2.f*ms*mean*mean + ms*ms*mean*mean;
  float sc = gn_w[k] / sqrtf(var + 1e-5f);
  scale[i] = sc;
  shift[i] = gn_b[k] - sc*mean*ms;
}

// K8: normalize
__global__ void k_norm(const float* __restrict__ h_gat, const int* __restrict__ batch,
                       const float* __restrict__ scale, const float* __restrict__ shift,
                       float* h_norm, int N){
  int gid = blockIdx.x*blockDim.x + threadIdx.x;
  if (gid >= N*KK) return;
  int n = gid >> 6, k = gid & 63;
  int b = batch[n];
  h_norm[gid] = scale[b*KK+k]*h_gat[gid] + shift[b*KK+k];
}

// K9: SAGE neighbor scatter (real edges only)
__global__ void k_sageagg(const int* __restrict__ ei, const float* __restrict__ h_norm,
                          float* neigh, int E){
  int tid = blockIdx.x*blockDim.x + threadIdx.x;
  if (tid >= E*16) return;
  int e = tid >> 4, q = tid & 15;
  int s = ei[e], d = ei[E+e];
  const float4 v = *(const float4*)(h_norm + (size_t)s*KK + q*4);
  float* o = neigh + (size_t)d*KK + q*4;
  atomicAdd(o+0, v.x); atomicAdd(o+1, v.y);
  atomicAdd(o+2, v.z); atomicAdd(o+3, v.w);
}

// K10: SAGE matmul + relu + pooling accumulation (4 nodes / 256-thread block)
__global__ void k_sagemm(const float* __restrict__ neigh, const float* __restrict__ h_norm,
                         const float* __restrict__ deg, const int* __restrict__ batch,
                         const float* __restrict__ Wl, const float* __restrict__ bln,
                         const float* __restrict__ Wr,
                         unsigned* gmax, float* gpool, int N){
  __shared__ float snm[4][KK], shn[4][KK];
  int u = threadIdx.x >> 6, j = threadIdx.x & 63;
  int n = blockIdx.x*4 + u;
  if (n < N){
    float dg = fmaxf(deg[n], 1.0f);
    snm[u][j] = neigh[(size_t)n*KK+j] / dg;
    shn[u][j] = h_norm[(size_t)n*KK+j];
  }
  __syncthreads();
  if (n >= N) return;
  float acc = bln[j];
  #pragma unroll
  for (int k = 0; k < KK; ++k){
    acc = fmaf(snm[u][k], Wl[k*KK+j], acc);
    acc = fmaf(shn[u][k], Wr[k*KK+j], acc);
  }
  acc = fmaxf(acc, 0.f);
  int b = batch[n];
  atomicMax(&gmax[b*KK+j], __float_as_uint(acc));  // acc>=0: bit order == value order
  atomicAdd(&gpool[b*KK+j], acc);
}

// K11: pooled feature vector [gmax, gmean]
__global__ void k_pool(const unsigned* __restrict__ gmax, const float* __restrict__ gpool,
                       const float* __restrict__ gcnt, float* gvec){
  int i = blockIdx.x*blockDim.x + threadIdx.x;
  if (i >= GG*128) return;
  int g = i >> 7, j = i & 127;
  gvec[i] = (j < 64) ? __uint_as_float(gmax[g*64+j])
                     : gpool[g*64 + (j-64)] / fmaxf(gcnt[g], 1.0f);
}

// K12: dense layer, one thread per output element
__global__ void k_fc(const float* __restrict__ in, const float* __restrict__ W,
                     const float* __restrict__ b, float* out, int In, int Out, int doRelu){
  int i = blockIdx.x*blockDim.x + threadIdx.x;
  if (i >= GG*Out) return;
  int g = i / Out, j = i - g*Out;
  const float* row = in + (size_t)g*In;
  float acc = b[j];
  for (int k = 0; k < In; ++k) acc = fmaf(row[k], W[(size_t)k*Out + j], acc);
  if (doRelu) acc = fmaxf(acc, 0.f);
  out[i] = acc;
}

extern "C" void kernel_launch(void* const* d_in, const int* in_sizes, int n_in,
                              void* d_out, int out_size, void* d_ws, size_t ws_size,
                              hipStream_t stream) {
  const float* x        = (const float*)d_in[0];
  const int*   ei       = (const int*)d_in[1];
  const float* ea       = (const float*)d_in[2];
  const int*   batch    = (const int*)d_in[3];
  const float* Wl       = (const float*)d_in[4];
  const float* bl       = (const float*)d_in[5];
  const float* Wr       = (const float*)d_in[6];
  const float* br       = (const float*)d_in[7];
  const float* We       = (const float*)d_in[8];
  const float* att      = (const float*)d_in[9];
  const float* gat_bias = (const float*)d_in[10];
  const float* gn_w     = (const float*)d_in[11];
  const float* gn_b     = (const float*)d_in[12];
  const float* gn_ms    = (const float*)d_in[13];
  const float* sage_Wl  = (const float*)d_in[14];
  const float* sage_bl  = (const float*)d_in[15];
  const float* sage_Wr  = (const float*)d_in[16];
  const float* fc1_W    = (const float*)d_in[17];
  const float* fc1_b    = (const float*)d_in[18];
  const float* fc2_W    = (const float*)d_in[19];
  const float* fc2_b    = (const float*)d_in[20];
  const float* fc3_W    = (const float*)d_in[21];
  const float* fc3_b    = (const float*)d_in[22];

  const int N = in_sizes[0];
  const int E = in_sizes[1] / 2;

  float* ws = (float*)d_ws;
  size_t off = 0;
  auto alloc = [&](size_t n){ float* p = ws + off; off += n; return p; };

  float* deg   = alloc(N);
  float* asum  = alloc(N);            // becomes loop_attr
  float* smax  = alloc((size_t)N*HH); // uint during K3, float after K4
  float* denom = alloc((size_t)N*HH);
  float* S1    = alloc((size_t)N*HH);
  float* gsum  = alloc(GG*KK);
  float* gsum2 = alloc(GG*KK);
  float* gcnt  = alloc(GG);
  float* neigh = alloc((size_t)N*KK);
  unsigned* gmax = (unsigned*)alloc(GG*KK);
  float* gpool = alloc(GG*KK);
  size_t zero_floats = off;           // everything above is zero-initialized
  float* h_gat  = alloc((size_t)N*KK);
  float* h_norm = alloc((size_t)N*KK);
  float* scale  = alloc(GG*KK);
  float* shift  = alloc(GG*KK);
  float* gvec   = alloc(GG*128);
  float* out1   = alloc(GG*2048);
  float* out2   = alloc(GG*1024);
  (void)ws_size; (void)n_in; (void)out_size;

  hipMemsetAsync(d_ws, 0, zero_floats*sizeof(float), stream);

  const int B = 256;
  k_deg<<<(E+B-1)/B, B, 0, stream>>>(ei, ea, deg, asum, E);
  k_loopattr<<<(N+B-1)/B, B, 0, stream>>>(asum, deg, N);
  {
    int T = E + N;
    k_scoremax<<<(T+B-1)/B, B, 0, stream>>>(x, ei, ea, asum, Wl, bl, Wr, br, We, att,
                                            (unsigned*)smax, N, E);
    k_unmap<<<(N*HH+B-1)/B, B, 0, stream>>>((unsigned*)smax, N*HH);
    k_scoreacc<<<(T+B-1)/B, B, 0, stream>>>(x, ei, ea, asum, Wl, bl, Wr, br, We, att,
                                            smax, denom, S1, N, E);
  }
  k_gatout<<<((size_t)N*KK+B-1)/B, B, 0, stream>>>(S1, denom, batch, Wl, bl, gat_bias,
                                                   h_gat, gsum, gsum2, gcnt, N);
  k_gncoef<<<(GG*KK+B-1)/B, B, 0, stream>>>(gsum, gsum2, gcnt, gn_w, gn_b, gn_ms, scale, shift);
  k_norm<<<((size_t)N*KK+B-1)/B, B, 0, stream>>>(h_gat, batch, scale, shift, h_norm, N);
  k_sageagg<<<((size_t)E*16+B-1)/B, B, 0, stream>>>(ei, h_norm, neigh, E);
  k_sagemm<<<(N+3)/4, B, 0, stream>>>(neigh, h_norm, deg, batch, sage_Wl, sage_bl, sage_Wr,
                                      gmax, gpool, N);
  k_pool<<<(GG*128+B-1)/B, B, 0, stream>>>(gmax, gpool, gcnt, gvec);
  k_fc<<<(GG*2048+B-1)/B, B, 0, stream>>>(gvec, fc1_W, fc1_b, out1, 128, 2048, 1);
  k_fc<<<(GG*1024+B-1)/B, B, 0, stream>>>(out1, fc2_W, fc2_b, out2, 2048, 1024, 1);
  k_fc<<<(GG*3+B-1)/B, B, 0, stream>>>(out2, fc3_W, fc3_b, (float*)d_out, 1024, 3, 0);
}

// Round 2
// 564.901 us; speedup vs baseline: 6.6417x; 6.6417x over previous
//
#include <hip/hip_runtime.h>

#define GG 64
#define HH 16
#define KK 64   // H*C

// ---------- CSR build ----------

// count in-degree
__global__ void k_count(const int* __restrict__ ei, int* deg, int E){
  int e = blockIdx.x*blockDim.x + threadIdx.x;
  if (e < E) atomicAdd(&deg[ei[E + e]], 1);
}

// single-block exclusive scan of deg -> row_start[0..N]
__global__ void k_scan(const int* __restrict__ deg, int* __restrict__ row_start, int N){
  __shared__ int wsum[16];
  __shared__ int carry;
  int lane = threadIdx.x & 63, wv = threadIdx.x >> 6;
  if (threadIdx.x == 0) carry = 0;
  __syncthreads();
  for (int base = 0; base < N; base += 1024){
    int i = base + (int)threadIdx.x;
    int v = (i < N) ? deg[i] : 0;
    // inclusive wave scan
    int val = v;
    #pragma unroll
    for (int ofs = 1; ofs < 64; ofs <<= 1){
      int t = __shfl_up(val, ofs, 64);
      if (lane >= ofs) val += t;
    }
    if (lane == 63) wsum[wv] = val;
    __syncthreads();
    if (threadIdx.x == 0){
      int run = carry;
      #pragma unroll
      for (int w = 0; w < 16; ++w){ int t = wsum[w]; wsum[w] = run; run += t; }
      carry = run;
    }
    __syncthreads();
    if (i < N) row_start[i] = wsum[wv] + val - v;   // exclusive
    __syncthreads();
  }
  if (threadIdx.x == 0) row_start[N] = carry;
}

// scatter edges into CSR slots
__global__ void k_scatter(const int* __restrict__ ei, const float* __restrict__ ea,
                          const int* __restrict__ row_start, int* cursor,
                          int* csr_src, float* csr_ea, int E){
  int e = blockIdx.x*blockDim.x + threadIdx.x;
  if (e >= E) return;
  int d = ei[E + e];
  int pos = row_start[d] + atomicAdd(&cursor[d], 1);
  csr_src[pos] = ei[e];
  csr_ea[pos]  = ea[e];
}

// ---------- GAT: one gather pass, online softmax, 16 lanes/node (1 per head) ----------
__global__ void k_gat(const float* __restrict__ x, const int* __restrict__ row_start,
                      const int* __restrict__ csr_src, const float* __restrict__ csr_ea,
                      const float* __restrict__ Wl, const float* __restrict__ bl,
                      const float* __restrict__ Wr, const float* __restrict__ br,
                      const float* __restrict__ We, const float* __restrict__ att,
                      const float* __restrict__ gat_bias,
                      float* __restrict__ h, int N){
  int t = blockIdx.x*blockDim.x + threadIdx.x;
  int n  = t >> 4;
  int hh = t & 15;
  if (n >= N) return;
  float xd = x[n];
  float wl[4], we[4], at[4], pre[4], ob[4];
  #pragma unroll
  for (int c = 0; c < 4; ++c){
    int k = hh*4 + c;
    wl[c] = Wl[k]; we[c] = We[k]; at[c] = att[k];
    pre[c] = bl[k] + fmaf(xd, Wr[k], br[k]);   // bl + xd*Wr + br
    ob[c]  = bl[k] + gat_bias[k];
  }
  int e0 = row_start[n], e1 = row_start[n+1];
  float m = -3.4e38f, den = 0.f, S1 = 0.f, asum = 0.f;
  for (int e = e0; e < e1; ++e){
    int s = csr_src[e];
    float eav = csr_ea[e];
    float xs = x[s];
    asum += eav;
    float sc = 0.f;
    #pragma unroll
    for (int c = 0; c < 4; ++c){
      float tt = fmaf(xs, wl[c], fmaf(eav, we[c], pre[c]));
      tt = (tt > 0.f) ? tt : 0.2f*tt;
      sc = fmaf(tt, at[c], sc);
    }
    float nm = fmaxf(m, sc);
    float corr = __expf(m - nm);
    float a    = __expf(sc - nm);
    den = den*corr + a;
    S1  = S1 *corr + a*xs;
    m = nm;
  }
  { // self loop
    float degf = (float)(e1 - e0);
    float eav = asum / fmaxf(degf, 1.0f);
    float xs = xd;
    float sc = 0.f;
    #pragma unroll
    for (int c = 0; c < 4; ++c){
      float tt = fmaf(xs, wl[c], fmaf(eav, we[c], pre[c]));
      tt = (tt > 0.f) ? tt : 0.2f*tt;
      sc = fmaf(tt, at[c], sc);
    }
    float nm = fmaxf(m, sc);
    float corr = __expf(m - nm);
    float a    = __expf(sc - nm);
    den = den*corr + a;
    S1  = S1 *corr + a*xs;
  }
  float r = S1 / den;
  float4 o;
  o.x = fmaxf(fmaf(wl[0], r, ob[0]), 0.f);
  o.y = fmaxf(fmaf(wl[1], r, ob[1]), 0.f);
  o.z = fmaxf(fmaf(wl[2], r, ob[2]), 0.f);
  o.w = fmaxf(fmaf(wl[3], r, ob[3]), 0.f);
  *(float4*)(h + (size_t)n*KK + hh*4) = o;
}

// ---------- GroupNorm stats + coefficients: 1 block per group ----------
__global__ void __launch_bounds__(1024)
k_gstats(const float* __restrict__ h, const int* __restrict__ batch, int N,
         const float* __restrict__ gn_w, const float* __restrict__ gn_b,
         const float* __restrict__ gn_ms,
         float* __restrict__ scale, float* __restrict__ shift){
  int g = blockIdx.x;
  int lo = 0, hi = N;
  while (lo < hi){ int mid = (lo+hi) >> 1; if (batch[mid] < g) lo = mid+1; else hi = mid; }
  int s = lo;
  lo = s; hi = N;
  while (lo < hi){ int mid = (lo+hi) >> 1; if (batch[mid] < g+1) lo = mid+1; else hi = mid; }
  int epos = lo;
  int k = threadIdx.x & 63, slice = threadIdx.x >> 6;  // 16 slices
  float sum = 0.f, sum2 = 0.f;
  for (int n = s + slice; n < epos; n += 16){
    float v = h[(size_t)n*KK + k];
    sum += v; sum2 += v*v;
  }
  __shared__ float ls[16][KK], ls2[16][KK];
  ls[slice][k] = sum; ls2[slice][k] = sum2;
  __syncthreads();
  for (int st = 8; st >= 1; st >>= 1){
    if (slice < st){ ls[slice][k] += ls[slice+st][k]; ls2[slice][k] += ls2[slice+st][k]; }
    __syncthreads();
  }
  if (slice == 0){
    float c = fmaxf((float)(epos - s), 1.0f);
    float mean = ls[0][k]/c, eh2 = ls2[0][k]/c;
    float ms = gn_ms[k];
    float var = eh2 - 2.f*ms*mean*mean + ms*ms*mean*mean;
    float sc = gn_w[k] / sqrtf(var + 1e-5f);
    scale[g*KK + k] = sc;
    shift[g*KK + k] = gn_b[k] - sc*mean*ms;
  }
}

// ---------- normalize in place ----------
__global__ void k_norm(float* __restrict__ h, const int* __restrict__ batch,
                       const float* __restrict__ scale, const float* __restrict__ shift, int N){
  int gid = blockIdx.x*blockDim.x + threadIdx.x;
  if (gid >= N*KK) return;
  int n = gid >> 6, k = gid & 63;
  int b = batch[n];
  h[gid] = fmaf(scale[b*KK + k], h[gid], shift[b*KK + k]);
}

// ---------- SAGE: gather mean + dual matmul fused, 4 nodes per 256-thread block ----------
__global__ void k_sage(const float* __restrict__ h, const int* __restrict__ row_start,
                       const int* __restrict__ csr_src,
                       const float* __restrict__ Wl, const float* __restrict__ bln,
                       const float* __restrict__ Wr,
                       float* __restrict__ h2, int N){
  __shared__ float snm[4][KK], shn[4][KK];
  int u = threadIdx.x >> 6, j = threadIdx.x & 63;
  int n = blockIdx.x*4 + u;
  if (n < N){
    int e0 = row_start[n], e1 = row_start[n+1];
    float acc = 0.f;
    for (int e = e0; e < e1; ++e){
      int s = csr_src[e];
      acc += h[(size_t)s*KK + j];
    }
    float dg = fmaxf((float)(e1 - e0), 1.0f);
    snm[u][j] = acc / dg;
    shn[u][j] = h[(size_t)n*KK + j];
  }
  __syncthreads();
  if (n >= N) return;
  float acc = bln[j];
  #pragma unroll
  for (int k = 0; k < KK; ++k){
    acc = fmaf(snm[u][k], Wl[k*KK + j], acc);
    acc = fmaf(shn[u][k], Wr[k*KK + j], acc);
  }
  h2[(size_t)n*KK + j] = fmaxf(acc, 0.f);
}

// ---------- pooling: 1 block per group -> gvec[g][0:64]=max, [64:128]=mean ----------
__global__ void __launch_bounds__(1024)
k_pool(const float* __restrict__ h2, const int* __restrict__ batch, int N,
       float* __restrict__ gvec){
  int g = blockIdx.x;
  int lo = 0, hi = N;
  while (lo < hi){ int mid = (lo+hi) >> 1; if (batch[mid] < g) lo = mid+1; else hi = mid; }
  int s = lo;
  lo = s; hi = N;
  while (lo < hi){ int mid = (lo+hi) >> 1; if (batch[mid] < g+1) lo = mid+1; else hi = mid; }
  int epos = lo;
  int k = threadIdx.x & 63, slice = threadIdx.x >> 6;
  float mx = -3.4e38f, sm = 0.f;
  for (int n = s + slice; n < epos; n += 16){
    float v = h2[(size_t)n*KK + k];
    mx = fmaxf(mx, v); sm += v;
  }
  __shared__ float lm[16][KK], lsum[16][KK];
  lm[slice][k] = mx; lsum[slice][k] = sm;
  __syncthreads();
  for (int st = 8; st >= 1; st >>= 1){
    if (slice < st){
      lm[slice][k] = fmaxf(lm[slice][k], lm[slice+st][k]);
      lsum[slice][k] += lsum[slice+st][k];
    }
    __syncthreads();
  }
  if (slice == 0){
    float c = fmaxf((float)(epos - s), 1.0f);
    gvec[g*128 + k]      = lm[0][k];
    gvec[g*128 + 64 + k] = lsum[0][k] / c;
  }
}

// ---------- dense layers ----------
__global__ void k_fc(const float* __restrict__ in, const float* __restrict__ W,
                     const float* __restrict__ b, float* out, int In, int Out, int doRelu){
  int i = blockIdx.x*blockDim.x + threadIdx.x;
  if (i >= GG*Out) return;
  int g = i / Out, j = i - g*Out;
  const float* row = in + (size_t)g*In;
  float acc = b[j];
  for (int k = 0; k < In; ++k) acc = fmaf(row[k], W[(size_t)k*Out + j], acc);
  if (doRelu) acc = fmaxf(acc, 0.f);
  out[i] = acc;
}

// fc2 with g-tiling: block = 16 j x 16 g; grid = (1024/16, 64/16)
__global__ void k_fc2(const float* __restrict__ in, const float* __restrict__ W,
                      const float* __restrict__ b, float* __restrict__ out){
  int jl = threadIdx.x & 15, gl = threadIdx.x >> 4;
  int j = blockIdx.x*16 + jl;
  int g = blockIdx.y*16 + gl;
  const float* inr = in + (size_t)g*2048;
  float acc = b[j];
  for (int k = 0; k < 2048; ++k)
    acc = fmaf(inr[k], W[(size_t)k*1024 + j], acc);
  out[(size_t)g*1024 + j] = fmaxf(acc, 0.f);
}

extern "C" void kernel_launch(void* const* d_in, const int* in_sizes, int n_in,
                              void* d_out, int out_size, void* d_ws, size_t ws_size,
                              hipStream_t stream) {
  const float* x        = (const float*)d_in[0];
  const int*   ei       = (const int*)d_in[1];
  const float* ea       = (const float*)d_in[2];
  const int*   batch    = (const int*)d_in[3];
  const float* Wl       = (const float*)d_in[4];
  const float* bl       = (const float*)d_in[5];
  const float* Wr       = (const float*)d_in[6];
  const float* br       = (const float*)d_in[7];
  const float* We       = (const float*)d_in[8];
  const float* att      = (const float*)d_in[9];
  const float* gat_bias = (const float*)d_in[10];
  const float* gn_w     = (const float*)d_in[11];
  const float* gn_b     = (const float*)d_in[12];
  const float* gn_ms    = (const float*)d_in[13];
  const float* sage_Wl  = (const float*)d_in[14];
  const float* sage_bl  = (const float*)d_in[15];
  const float* sage_Wr  = (const float*)d_in[16];
  const float* fc1_W    = (const float*)d_in[17];
  const float* fc1_b    = (const float*)d_in[18];
  const float* fc2_W    = (const float*)d_in[19];
  const float* fc2_b    = (const float*)d_in[20];
  const float* fc3_W    = (const float*)d_in[21];
  const float* fc3_b    = (const float*)d_in[22];

  const int N = in_sizes[0];
  const int E = in_sizes[1] / 2;

  char* ws = (char*)d_ws;
  size_t off = 0;
  auto alloc = [&](size_t bytes){ void* p = ws + off; off += (bytes + 255) & ~(size_t)255; return p; };

  int*   deg_i     = (int*)alloc((size_t)N*4);      // zeroed
  int*   cursor    = (int*)alloc((size_t)N*4);      // zeroed
  size_t zero_bytes = off;
  int*   row_start = (int*)alloc((size_t)(N+1)*4);
  int*   csr_src   = (int*)alloc((size_t)E*4);
  float* csr_ea    = (float*)alloc((size_t)E*4);
  float* h         = (float*)alloc((size_t)N*KK*4);
  float* h2        = (float*)alloc((size_t)N*KK*4);
  float* scale     = (float*)alloc(GG*KK*4);
  float* shift     = (float*)alloc(GG*KK*4);
  float* gvec      = (float*)alloc(GG*128*4);
  float* out1      = (float*)alloc((size_t)GG*2048*4);
  float* out2      = (float*)alloc((size_t)GG*1024*4);
  (void)ws_size; (void)n_in; (void)out_size;

  hipMemsetAsync(d_ws, 0, zero_bytes, stream);

  const int B = 256;
  k_count  <<<(E+B-1)/B, B, 0, stream>>>(ei, deg_i, E);
  k_scan   <<<1, 1024, 0, stream>>>(deg_i, row_start, N);
  k_scatter<<<(E+B-1)/B, B, 0, stream>>>(ei, ea, row_start, cursor, csr_src, csr_ea, E);
  k_gat    <<<((size_t)N*16+B-1)/B, B, 0, stream>>>(x, row_start, csr_src, csr_ea,
                                                    Wl, bl, Wr, br, We, att, gat_bias, h, N);
  k_gstats <<<GG, 1024, 0, stream>>>(h, batch, N, gn_w, gn_b, gn_ms, scale, shift);
  k_norm   <<<((size_t)N*KK+B-1)/B, B, 0, stream>>>(h, batch, scale, shift, N);
  k_sage   <<<(N+3)/4, B, 0, stream>>>(h, row_start, csr_src, sage_Wl, sage_bl, sage_Wr, h2, N);
  k_pool   <<<GG, 1024, 0, stream>>>(h2, batch, N, gvec);
  k_fc     <<<(GG*2048+B-1)/B, B, 0, stream>>>(gvec, fc1_W, fc1_b, out1, 128, 2048, 1);
  {
    dim3 grid(1024/16, GG/16);
    k_fc2  <<<grid, 256, 0, stream>>>(out1, fc2_W, fc2_b, out2);
  }
  k_fc     <<<(GG*3+B-1)/B, B, 0, stream>>>(out2, fc3_W, fc3_b, (float*)d_out, 1024, 3, 0);
}